// Round 3
// baseline (587.254 us; speedup 1.0000x reference)
//
#include <hip/hip_runtime.h>
#include <hip/hip_bf16.h>

// GroupedEmbeddingBag: T=8 tables [V=100000, D=128] fp32, B=4096 bags/table.
// out[b, t*D+d] = sum_{i in [offs[t][b], offs[t][b+1])} tables[t][values[t][i]][d] * psw[t][i]
//
// R2: true ping-pong software pipeline. One WAVE per bag; each row gather is
// one wave-load: 64 lanes x float2 = 512B contiguous. Groups of 8 rows are
// double-buffered A/B with NO copy-rotate: while consuming group A's FMAs,
// group B's 8 gathers (+ meta) are already in flight, and vice versa ->
// 8-16 x 512B continuously outstanding per wave. Indices/weights are
// wave-uniform loads (L1-hot, compiler may scalarize to s_load).

namespace {
constexpr int T = 8;
constexpr int V = 100000;
constexpr int D = 128;
constexpr int B = 4096;
constexpr int N = 204800;
}

__global__ __launch_bounds__(256) void grouped_ebag_kernel(
    const float* __restrict__ tables,   // [T, V, D]
    const int* __restrict__ values,     // [T, N]
    const int* __restrict__ offsets,    // [T, B+1]
    const float* __restrict__ psw,      // [T, N]
    float* __restrict__ out)            // [B, T*D]
{
    const int wave = threadIdx.x >> 6;            // 0..3
    const int lane = threadIdx.x & 63;
    const int bag  = (blockIdx.x << 2) + wave;    // (t, b) ordered
    const int t = bag >> 12;                      // B = 4096
    const int b = bag & (B - 1);

    const int start = offsets[t * (B + 1) + b];
    const int end   = offsets[t * (B + 1) + b + 1];
    const int len   = end - start;

    const float2* __restrict__ tab2 = (const float2*)(tables + (size_t)t * (V * D));
    const int*    __restrict__ vals = values + (size_t)t * N;
    const float*  __restrict__ wgt  = psw    + (size_t)t * N;

    float2 acc = make_float2(0.f, 0.f);

    // Load meta + issue 8 row-gathers for one group starting at row index ii.
    auto load_group = [&](int ii, float* w, float2* d) {
        int v[8];
#pragma unroll
        for (int j = 0; j < 8; ++j) {
            v[j] = vals[ii + j];
            w[j] = wgt [ii + j];
        }
#pragma unroll
        for (int j = 0; j < 8; ++j) {
            d[j] = tab2[(v[j] << 6) + lane];
        }
    };
    auto consume = [&](const float* w, const float2* d) {
#pragma unroll
        for (int j = 0; j < 8; ++j) {
            acc.x = fmaf(d[j].x, w[j], acc.x);
            acc.y = fmaf(d[j].y, w[j], acc.y);
        }
    };

    const int ngrp = len >> 3;   // groups of 8 rows
    if (ngrp >= 1) {
        float wA[8]; float2 dA[8];
        float wB[8]; float2 dB[8];
        load_group(start, wA, dA);
        int g = 1;
        for (; g + 1 < ngrp; g += 2) {
            load_group(start + (g << 3), wB, dB);       // B in flight
            consume(wA, dA);                            // wait A only
            load_group(start + ((g + 1) << 3), wA, dA); // A' in flight
            consume(wB, dB);                            // wait B only
        }
        if (g < ngrp) {
            load_group(start + (g << 3), wB, dB);
            consume(wA, dA);
            consume(wB, dB);
        } else {
            consume(wA, dA);
        }
    }

    // Remainder rows (< 8).
    for (int i = start + (ngrp << 3); i < end; ++i) {
        const int   v = vals[i];
        const float w = wgt[i];
        const float2 e = tab2[(v << 6) + lane];
        acc.x = fmaf(e.x, w, acc.x);
        acc.y = fmaf(e.y, w, acc.y);
    }

    // 64 lanes x 8B = 512B coalesced store per bag.
    *(float2*)(out + (size_t)b * (T * D) + t * D + lane * 2) = acc;
}

extern "C" void kernel_launch(void* const* d_in, const int* in_sizes, int n_in,
                              void* d_out, int out_size, void* d_ws, size_t ws_size,
                              hipStream_t stream) {
    const float* tables  = (const float*)d_in[0];
    const int*   values  = (const int*)d_in[1];
    const int*   offsets = (const int*)d_in[2];
    const float* psw     = (const float*)d_in[3];
    float*       out     = (float*)d_out;

    dim3 grid((T * B) / 4);   // 4 bags (waves) per 256-thread block
    dim3 block(256);
    grouped_ebag_kernel<<<grid, block, 0, stream>>>(tables, values, offsets, psw, out);
}